// Round 8
// baseline (142.916 us; speedup 1.0000x reference)
//
#include <hip/hip_runtime.h>
#include <math.h>

#define B_ 16
#define S_ 2048
#define IN_DIM 128
#define E2 6
#define E_ 3
#define OUT_DIM 64

// ws layout:
//   [0, B*S*4 floats)  : h as float4 (x,y,z, sq=|h|^2)   = 524288 B
//   then 64 ints       : per batch {max_d2_bits, total, diag, vert}
//
// R5/R6 lesson: NO manually-staged row arrays (spill -> 700 MB scratch
// traffic). Rows read from LDS one at a time, partial unroll only.
// R8: rows prescaled in LDS as (-2x,-2y,-2z,sq) -> 3 fma per pair;
// 32-row spans -> 2048 blocks = 8 blocks/CU for latency hiding.

// one wave per row: 64 lanes x float2 = 128 inputs. Block 0 also zeroes acc.
__global__ __launch_bounds__(256) void embed_kernel(
    const float* __restrict__ x, const float* __restrict__ w1,
    const float* __restrict__ b1, const float* __restrict__ w2,
    const float* __restrict__ b2, float* __restrict__ hws,
    int* __restrict__ acc)
{
    if (blockIdx.x == 0 && threadIdx.x < 64) acc[threadIdx.x] = 0;
    int wave = threadIdx.x >> 6;
    int lane = threadIdx.x & 63;
    int row  = blockIdx.x * 4 + wave;            // [0, B*S)
    const float2* x2 = (const float2*)(x + (size_t)row * IN_DIM);
    float2 xv = x2[lane];
    const float* w1a = w1 + (2 * lane) * E2;     // 12 contiguous floats
    float a[E2];
#pragma unroll
    for (int q = 0; q < E2; ++q)
        a[q] = xv.x * w1a[q] + xv.y * w1a[E2 + q];
#pragma unroll
    for (int q = 0; q < E2; ++q) {
#pragma unroll
        for (int off = 32; off >= 1; off >>= 1)
            a[q] += __shfl_xor(a[q], off, 64);
    }
    if (lane == 0) {
        float r[E2];
#pragma unroll
        for (int q = 0; q < E2; ++q) r[q] = fmaxf(a[q] + b1[q], 0.f);
        float h[E_];
#pragma unroll
        for (int e = 0; e < E_; ++e) {
            float s = b2[e];
#pragma unroll
            for (int q = 0; q < E2; ++q) s += r[q] * w2[q * E_ + e];
            h[e] = s;
        }
        float sq = h[0] * h[0] + h[1] * h[1] + h[2] * h[2];
        ((float4*)hws)[row] = make_float4(h[0], h[1], h[2], sq);
    }
}

// grid: B * 2 colBlocks * 64 rowSpans = 2048 blocks of 256 (8 blocks/CU).
// thread = 4 columns (stride 256); 32-row span prescaled into LDS as
// (-2x,-2y,-2z,sq): t = sq_r - 2*dot = 3 chained fma.
// d2 < thr2  <=>  t < thr2 - sq_c.  Symmetry prune for the max.
__global__ __launch_bounds__(256) void max_kernel(
    const float4* __restrict__ h4, int* __restrict__ acc)
{
    int bid = blockIdx.x;
    int b  = bid >> 7;
    int cb = (bid >> 6) & 1;
    int rb = bid & 63;
    int r0 = rb * 32;
    int c0 = cb * 1024;
    if (r0 > c0 + 1023) return;                  // row>col half: mirrored elsewhere
    const float4* hb = h4 + (size_t)b * S_;
    __shared__ float4 sh[32];
    if (threadIdx.x < 32) {
        float4 rv = hb[r0 + threadIdx.x];
        sh[threadIdx.x] = make_float4(-2.f * rv.x, -2.f * rv.y, -2.f * rv.z, rv.w);
    }
    float4 hj[4];
#pragma unroll
    for (int c = 0; c < 4; ++c) hj[c] = hb[c0 + c * 256 + threadIdx.x];
    __syncthreads();
    float mc[4] = {-1e30f, -1e30f, -1e30f, -1e30f};
#pragma unroll 4
    for (int k = 0; k < 32; ++k) {
        float4 rv = sh[k];                       // broadcast, 4 VGPRs live
#pragma unroll
        for (int c = 0; c < 4; ++c) {
            float t = fmaf(hj[c].x, rv.x,
                      fmaf(hj[c].y, rv.y,
                      fmaf(hj[c].z, rv.z, rv.w)));   // sq_r - 2 dot
            mc[c] = fmaxf(mc[c], t);
        }
    }
    float m = fmaxf(fmaxf(mc[0] + hj[0].w, mc[1] + hj[1].w),
                    fmaxf(mc[2] + hj[2].w, mc[3] + hj[3].w));
    m = fmaxf(m, 0.f);                           // d2 >= 0
#pragma unroll
    for (int off = 32; off >= 1; off >>= 1)
        m = fmaxf(m, __shfl_xor(m, off, 64));
    __shared__ float wmax[4];
    int lane = threadIdx.x & 63, wave = threadIdx.x >> 6;
    if (lane == 0) wmax[wave] = m;
    __syncthreads();
    if (threadIdx.x == 0) {
        float mm = fmaxf(fmaxf(wmax[0], wmax[1]), fmaxf(wmax[2], wmax[3]));
        atomicMax(&acc[b * 4 + 0], __float_as_int(mm));  // d2>=0: int order == float order
    }
}

__global__ __launch_bounds__(256) void stats_kernel(
    const float4* __restrict__ h4, const float* __restrict__ theta,
    int* __restrict__ acc)
{
    int bid = blockIdx.x;
    int b  = bid >> 7;
    int cb = (bid >> 6) & 1;
    int rb = bid & 63;
    int r0 = rb * 32;
    int c0 = cb * 1024;
    const float4* hb = h4 + (size_t)b * S_;
    __shared__ float4 sh[34];                    // sh[1+k] = row r0+k, prescaled
    if (threadIdx.x < 34) {
        int r = r0 - 1 + threadIdx.x;
        r = r < 0 ? 0 : (r >= S_ ? S_ - 1 : r);
        float4 rv = hb[r];
        sh[threadIdx.x] = make_float4(-2.f * rv.x, -2.f * rv.y, -2.f * rv.z, rv.w);
    }
    float4 hj[4];
#pragma unroll
    for (int c = 0; c < 4; ++c) hj[c] = hb[c0 + c * 256 + threadIdx.x];
    __syncthreads();
    float maxd2 = __int_as_float(acc[b * 4 + 0]);
    float sig   = 1.f / (1.f + expf(-theta[0]));
    float thr2  = sig * sig * maxd2;
    float thrc[4];
#pragma unroll
    for (int c = 0; c < 4; ++c) thrc[c] = thr2 - hj[c].w;  // d2<thr2 <=> t<thrc

    unsigned mk[4] = {0u, 0u, 0u, 0u};
#pragma unroll 4
    for (int k = 0; k < 32; ++k) {
        float4 rv = sh[1 + k];
        unsigned bitk = 1u << k;
#pragma unroll
        for (int c = 0; c < 4; ++c) {
            float t = fmaf(hj[c].x, rv.x,
                      fmaf(hj[c].y, rv.y,
                      fmaf(hj[c].z, rv.z, rv.w)));
            mk[c] |= (t < thrc[c]) ? bitk : 0u;
        }
    }

    int total = 0, diag = 0, vert = 0;
    float4 pr = sh[0], nx = sh[33];
#pragma unroll
    for (int c = 0; c < 4; ++c) {
        int j = c0 + c * 256 + threadIdx.x;
        unsigned m = mk[c];
        total += __popc(m);
        float tp = fmaf(hj[c].x, pr.x, fmaf(hj[c].y, pr.y, fmaf(hj[c].z, pr.z, pr.w)));
        float tn = fmaf(hj[c].x, nx.x, fmaf(hj[c].y, nx.y, fmaf(hj[c].z, nx.z, nx.w)));
        unsigned prevbit = (r0 > 0) ? ((tp < thrc[c]) ? 1u : 0u) : 0u;
        unsigned nextbit = (r0 + 32 < S_) ? ((tn < thrc[c]) ? 1u : 0u) : 0u;
        // vertical run starts: R[i] & ~R[i-1] & R[i+1]
        unsigned notprev = ~((m << 1) | prevbit);
        vert += __popc(m & notprev & ((m >> 1) | (nextbit << 31)));
        // diag band: rows s with j-s in [1,9] -> bits [j-9-r0, j-1-r0]
        int lo = j - 9 - r0, hi = j - 1 - r0;
        if (hi >= 0 && lo <= 31) {
            int l = lo < 0 ? 0 : lo;
            int h = hi > 31 ? 31 : hi;
            unsigned bandm = (unsigned)(((1ull << (h - l + 1)) - 1ull) << l);
            diag += __popc(m & bandm);
        }
    }

#pragma unroll
    for (int off = 32; off >= 1; off >>= 1) {
        total += __shfl_xor(total, off, 64);
        diag  += __shfl_xor(diag,  off, 64);
        vert  += __shfl_xor(vert,  off, 64);
    }
    __shared__ int wsum[4][3];
    int lane = threadIdx.x & 63, wave = threadIdx.x >> 6;
    if (lane == 0) { wsum[wave][0] = total; wsum[wave][1] = diag; wsum[wave][2] = vert; }
    __syncthreads();
    if (threadIdx.x == 0) {
        int t = 0, d = 0, v = 0;
#pragma unroll
        for (int w = 0; w < 4; ++w) { t += wsum[w][0]; d += wsum[w][1]; v += wsum[w][2]; }
        atomicAdd(&acc[b * 4 + 1], t);
        atomicAdd(&acc[b * 4 + 2], d);
        atomicAdd(&acc[b * 4 + 3], v);
    }
}

__global__ void finalize_kernel(const int* __restrict__ acc,
    const float* __restrict__ w3, const float* __restrict__ b3,
    float* __restrict__ out)
{
    int idx = blockIdx.x * 256 + threadIdx.x;    // 0..1023
    if (idx >= B_ * OUT_DIM) return;
    int b = idx >> 6, o = idx & 63;
    float total = (float)acc[b * 4 + 1];
    float diag  = (float)acc[b * 4 + 2];
    float vert  = (float)acc[b * 4 + 3];
    float rr  = total / (float)(S_ * S_);
    float det = diag / (total + 1e-6f);
    float lam = vert / (total + 1e-6f);
    float entr = -total * logf(1.0f + 1e-6f);    // fp32 semantics (verified absmax 0.0)
    float r = b3[o] + rr  * w3[0 * OUT_DIM + o]
                    + det * w3[1 * OUT_DIM + o]
                    + lam * w3[2 * OUT_DIM + o]
                    + entr * w3[3 * OUT_DIM + o];
    out[idx] = fmaxf(r, 0.f);
}

extern "C" void kernel_launch(void* const* d_in, const int* in_sizes, int n_in,
                              void* d_out, int out_size, void* d_ws, size_t ws_size,
                              hipStream_t stream) {
    const float* x     = (const float*)d_in[0];
    const float* theta = (const float*)d_in[1];
    const float* w1    = (const float*)d_in[2];
    const float* b1    = (const float*)d_in[3];
    const float* w2    = (const float*)d_in[4];
    const float* b2    = (const float*)d_in[5];
    const float* w3    = (const float*)d_in[6];
    const float* b3    = (const float*)d_in[7];
    float* out = (float*)d_out;
    float* hws = (float*)d_ws;
    int* acc = (int*)((char*)d_ws + (size_t)B_ * S_ * 4 * sizeof(float));

    hipLaunchKernelGGL(embed_kernel, dim3(B_ * S_ / 4), dim3(256), 0, stream,
                       x, w1, b1, w2, b2, hws, acc);
    hipLaunchKernelGGL(max_kernel, dim3(B_ * 128), dim3(256), 0, stream,
                       (const float4*)hws, acc);
    hipLaunchKernelGGL(stats_kernel, dim3(B_ * 128), dim3(256), 0, stream,
                       (const float4*)hws, theta, acc);
    hipLaunchKernelGGL(finalize_kernel, dim3(4), dim3(256), 0, stream, acc, w3, b3, out);
}

// Round 9
// 116.320 us; speedup vs baseline: 1.2286x; 1.2286x over previous
//
#include <hip/hip_runtime.h>
#include <math.h>

#define B_ 16
#define S_ 2048
#define IN_DIM 128
#define E2 6
#define E_ 3
#define OUT_DIM 64

// ws layout:
//   [0, B*S*4 floats)  : h as float4 (x,y,z, sq=|h|^2)   = 524288 B
//   then 64 ints       : per batch {max_d2_bits, total, diag, vert}
//
// R5/R6 lesson: NO manually-staged row arrays (spill -> 700 MB scratch).
// R8 lesson: small spans (32 rows, 2048 blocks) lose to per-block overhead;
// VALUBusy 21% == duty of (120cy LDS latency / ~50cy compute) -> the fix is
// VALU density per row read: 8 cols/thread (49 VALU per ds_read_b128),
// 64-row spans, 512 blocks.

// one wave per row: 64 lanes x float2 = 128 inputs. Block 0 also zeroes acc.
__global__ __launch_bounds__(256) void embed_kernel(
    const float* __restrict__ x, const float* __restrict__ w1,
    const float* __restrict__ b1, const float* __restrict__ w2,
    const float* __restrict__ b2, float* __restrict__ hws,
    int* __restrict__ acc)
{
    if (blockIdx.x == 0 && threadIdx.x < 64) acc[threadIdx.x] = 0;
    int wave = threadIdx.x >> 6;
    int lane = threadIdx.x & 63;
    int row  = blockIdx.x * 4 + wave;            // [0, B*S)
    const float2* x2 = (const float2*)(x + (size_t)row * IN_DIM);
    float2 xv = x2[lane];
    const float* w1a = w1 + (2 * lane) * E2;     // 12 contiguous floats
    float a[E2];
#pragma unroll
    for (int q = 0; q < E2; ++q)
        a[q] = xv.x * w1a[q] + xv.y * w1a[E2 + q];
#pragma unroll
    for (int q = 0; q < E2; ++q) {
#pragma unroll
        for (int off = 32; off >= 1; off >>= 1)
            a[q] += __shfl_xor(a[q], off, 64);
    }
    if (lane == 0) {
        float r[E2];
#pragma unroll
        for (int q = 0; q < E2; ++q) r[q] = fmaxf(a[q] + b1[q], 0.f);
        float h[E_];
#pragma unroll
        for (int e = 0; e < E_; ++e) {
            float s = b2[e];
#pragma unroll
            for (int q = 0; q < E2; ++q) s += r[q] * w2[q * E_ + e];
            h[e] = s;
        }
        float sq = h[0] * h[0] + h[1] * h[1] + h[2] * h[2];
        ((float4*)hws)[row] = make_float4(h[0], h[1], h[2], sq);
    }
}

// grid: B * 32 rowSpans = 512 blocks of 256 (2 blocks/CU).
// thread = 8 columns (stride 256, full 2048-col coverage); 64-row span
// prescaled into LDS as (-2x,-2y,-2z,sq): t = sq_r - 2*dot = 3 chained fma.
// d2 < thr2  <=>  t < thr2 - sq_c.
__global__ __launch_bounds__(256) void max_kernel(
    const float4* __restrict__ h4, int* __restrict__ acc)
{
    int bid = blockIdx.x;
    int b  = bid >> 5;
    int rb = bid & 31;
    int r0 = rb * 64;
    const float4* hb = h4 + (size_t)b * S_;
    __shared__ float4 sh[64];
    if (threadIdx.x < 64) {
        float4 rv = hb[r0 + threadIdx.x];
        sh[threadIdx.x] = make_float4(-2.f * rv.x, -2.f * rv.y, -2.f * rv.z, rv.w);
    }
    float4 hj[8];
#pragma unroll
    for (int c = 0; c < 8; ++c) hj[c] = hb[c * 256 + threadIdx.x];
    __syncthreads();
    float mc[8];
#pragma unroll
    for (int c = 0; c < 8; ++c) mc[c] = -1e30f;
#pragma unroll 2
    for (int k = 0; k < 64; ++k) {
        float4 rv = sh[k];                       // broadcast, 4 VGPRs live
#pragma unroll
        for (int c = 0; c < 8; ++c) {
            float t = fmaf(hj[c].x, rv.x,
                      fmaf(hj[c].y, rv.y,
                      fmaf(hj[c].z, rv.z, rv.w)));   // sq_r - 2 dot
            mc[c] = fmaxf(mc[c], t);
        }
    }
    float m = -1e30f;
#pragma unroll
    for (int c = 0; c < 8; ++c) m = fmaxf(m, mc[c] + hj[c].w);
    m = fmaxf(m, 0.f);                           // d2 >= 0
#pragma unroll
    for (int off = 32; off >= 1; off >>= 1)
        m = fmaxf(m, __shfl_xor(m, off, 64));
    __shared__ float wmax[4];
    int lane = threadIdx.x & 63, wave = threadIdx.x >> 6;
    if (lane == 0) wmax[wave] = m;
    __syncthreads();
    if (threadIdx.x == 0) {
        float mm = fmaxf(fmaxf(wmax[0], wmax[1]), fmaxf(wmax[2], wmax[3]));
        atomicMax(&acc[b * 4 + 0], __float_as_int(mm));  // d2>=0: int order == float order
    }
}

__global__ __launch_bounds__(256) void stats_kernel(
    const float4* __restrict__ h4, const float* __restrict__ theta,
    int* __restrict__ acc)
{
    int bid = blockIdx.x;
    int b  = bid >> 5;
    int rb = bid & 31;
    int r0 = rb * 64;
    const float4* hb = h4 + (size_t)b * S_;
    __shared__ float4 sh[66];                    // sh[1+k] = row r0+k, prescaled
    if (threadIdx.x < 66) {
        int r = r0 - 1 + threadIdx.x;
        r = r < 0 ? 0 : (r >= S_ ? S_ - 1 : r);
        float4 rv = hb[r];
        sh[threadIdx.x] = make_float4(-2.f * rv.x, -2.f * rv.y, -2.f * rv.z, rv.w);
    }
    float4 hj[8];
#pragma unroll
    for (int c = 0; c < 8; ++c) hj[c] = hb[c * 256 + threadIdx.x];
    __syncthreads();
    float maxd2 = __int_as_float(acc[b * 4 + 0]);
    float sig   = 1.f / (1.f + expf(-theta[0]));
    float thr2  = sig * sig * maxd2;
    float thrc[8];
#pragma unroll
    for (int c = 0; c < 8; ++c) thrc[c] = thr2 - hj[c].w;  // d2<thr2 <=> t<thrc

    unsigned long long mk[8];
#pragma unroll
    for (int c = 0; c < 8; ++c) mk[c] = 0ull;
#pragma unroll 2
    for (int k = 0; k < 64; ++k) {
        float4 rv = sh[1 + k];
#pragma unroll
        for (int c = 0; c < 8; ++c) {
            float t = fmaf(hj[c].x, rv.x,
                      fmaf(hj[c].y, rv.y,
                      fmaf(hj[c].z, rv.z, rv.w)));
            mk[c] |= (t < thrc[c]) ? (1ull << k) : 0ull;
        }
    }

    int total = 0, diag = 0, vert = 0;
    float4 pr = sh[0], nx = sh[65];
#pragma unroll
    for (int c = 0; c < 8; ++c) {
        int j = c * 256 + threadIdx.x;
        unsigned long long m = mk[c];
        total += __popcll(m);
        float tp = fmaf(hj[c].x, pr.x, fmaf(hj[c].y, pr.y, fmaf(hj[c].z, pr.z, pr.w)));
        float tn = fmaf(hj[c].x, nx.x, fmaf(hj[c].y, nx.y, fmaf(hj[c].z, nx.z, nx.w)));
        unsigned long long prevbit = (r0 > 0) ? ((tp < thrc[c]) ? 1ull : 0ull) : 0ull;
        unsigned long long nextbit = (r0 + 64 < S_) ? ((tn < thrc[c]) ? 1ull : 0ull) : 0ull;
        // vertical run starts: R[i] & ~R[i-1] & R[i+1]
        unsigned long long notprev = ~((m << 1) | prevbit);
        vert += __popcll(m & notprev & ((m >> 1) | (nextbit << 63)));
        // diag band: rows s with j-s in [1,9] -> bits [j-9-r0, j-1-r0]
        int lo = j - 9 - r0, hi = j - 1 - r0;
        if (hi >= 0 && lo <= 63) {
            int l = lo < 0 ? 0 : lo;
            int h = hi > 63 ? 63 : hi;
            unsigned long long bandm = ((1ull << (h - l + 1)) - 1ull) << l;
            diag += __popcll(m & bandm);
        }
    }

    // pack (diag,vert) into 16+16 bits: after 64-lane sum diag<=4608, vert<=16384
    int dv = (diag << 16) | vert;
#pragma unroll
    for (int off = 32; off >= 1; off >>= 1) {
        total += __shfl_xor(total, off, 64);
        dv    += __shfl_xor(dv,    off, 64);
    }
    __shared__ int wsum[4][2];
    int lane = threadIdx.x & 63, wave = threadIdx.x >> 6;
    if (lane == 0) { wsum[wave][0] = total; wsum[wave][1] = dv; }
    __syncthreads();
    if (threadIdx.x == 0) {
        int t = 0, d = 0, v = 0;
#pragma unroll
        for (int w = 0; w < 4; ++w) {
            t += wsum[w][0];
            d += wsum[w][1] >> 16;
            v += wsum[w][1] & 0xFFFF;
        }
        atomicAdd(&acc[b * 4 + 1], t);
        atomicAdd(&acc[b * 4 + 2], d);
        atomicAdd(&acc[b * 4 + 3], v);
    }
}

__global__ void finalize_kernel(const int* __restrict__ acc,
    const float* __restrict__ w3, const float* __restrict__ b3,
    float* __restrict__ out)
{
    int idx = blockIdx.x * 256 + threadIdx.x;    // 0..1023
    if (idx >= B_ * OUT_DIM) return;
    int b = idx >> 6, o = idx & 63;
    float total = (float)acc[b * 4 + 1];
    float diag  = (float)acc[b * 4 + 2];
    float vert  = (float)acc[b * 4 + 3];
    float rr  = total / (float)(S_ * S_);
    float det = diag / (total + 1e-6f);
    float lam = vert / (total + 1e-6f);
    float entr = -total * logf(1.0f + 1e-6f);    // fp32 semantics (verified absmax 0.0)
    float r = b3[o] + rr  * w3[0 * OUT_DIM + o]
                    + det * w3[1 * OUT_DIM + o]
                    + lam * w3[2 * OUT_DIM + o]
                    + entr * w3[3 * OUT_DIM + o];
    out[idx] = fmaxf(r, 0.f);
}

extern "C" void kernel_launch(void* const* d_in, const int* in_sizes, int n_in,
                              void* d_out, int out_size, void* d_ws, size_t ws_size,
                              hipStream_t stream) {
    const float* x     = (const float*)d_in[0];
    const float* theta = (const float*)d_in[1];
    const float* w1    = (const float*)d_in[2];
    const float* b1    = (const float*)d_in[3];
    const float* w2    = (const float*)d_in[4];
    const float* b2    = (const float*)d_in[5];
    const float* w3    = (const float*)d_in[6];
    const float* b3    = (const float*)d_in[7];
    float* out = (float*)d_out;
    float* hws = (float*)d_ws;
    int* acc = (int*)((char*)d_ws + (size_t)B_ * S_ * 4 * sizeof(float));

    hipLaunchKernelGGL(embed_kernel, dim3(B_ * S_ / 4), dim3(256), 0, stream,
                       x, w1, b1, w2, b2, hws, acc);
    hipLaunchKernelGGL(max_kernel, dim3(B_ * 32), dim3(256), 0, stream,
                       (const float4*)hws, acc);
    hipLaunchKernelGGL(stats_kernel, dim3(B_ * 32), dim3(256), 0, stream,
                       (const float4*)hws, theta, acc);
    hipLaunchKernelGGL(finalize_kernel, dim3(4), dim3(256), 0, stream, acc, w3, b3, out);
}

// Round 10
// 115.193 us; speedup vs baseline: 1.2407x; 1.0098x over previous
//
#include <hip/hip_runtime.h>
#include <math.h>

#define B_ 16
#define S_ 2048
#define IN_DIM 128
#define E2 6
#define E_ 3
#define OUT_DIM 64

// ws layout:
//   [0, B*S*4 floats)  : h as float4 (x,y,z, sq=|h|^2)   = 524288 B
//   then 64 ints       : per batch {max_d2_bits, total, diag, vert}
//
// R5/R6: no staged row arrays (spill). R8: small spans lose to overhead.
// R9 post-mortem: VALUBusy pinned ~25% across designs == exposed ds_read
// latency. R10: manual 2-deep prefetch rotation (rv/nx) + descending-k
// mask build (m = 2m + bit: 3 instr vs 5) with two 32-bit masks.

// one wave per 4 rows: grid 2048 blocks. Block 0 also zeroes acc.
__global__ __launch_bounds__(256) void embed_kernel(
    const float* __restrict__ x, const float* __restrict__ w1,
    const float* __restrict__ b1, const float* __restrict__ w2,
    const float* __restrict__ b2, float* __restrict__ hws,
    int* __restrict__ acc)
{
    if (blockIdx.x == 0 && threadIdx.x < 64) acc[threadIdx.x] = 0;
    int wave = threadIdx.x >> 6;
    int lane = threadIdx.x & 63;
#pragma unroll
    for (int rr = 0; rr < 4; ++rr) {
        int row = blockIdx.x * 16 + wave * 4 + rr;   // [0, B*S)
        const float2* x2 = (const float2*)(x + (size_t)row * IN_DIM);
        float2 xv = x2[lane];
        const float* w1a = w1 + (2 * lane) * E2;     // 12 contiguous floats
        float a[E2];
#pragma unroll
        for (int q = 0; q < E2; ++q)
            a[q] = xv.x * w1a[q] + xv.y * w1a[E2 + q];
#pragma unroll
        for (int q = 0; q < E2; ++q) {
#pragma unroll
            for (int off = 32; off >= 1; off >>= 1)
                a[q] += __shfl_xor(a[q], off, 64);
        }
        if (lane == 0) {
            float r[E2];
#pragma unroll
            for (int q = 0; q < E2; ++q) r[q] = fmaxf(a[q] + b1[q], 0.f);
            float h[E_];
#pragma unroll
            for (int e = 0; e < E_; ++e) {
                float s = b2[e];
#pragma unroll
                for (int q = 0; q < E2; ++q) s += r[q] * w2[q * E_ + e];
                h[e] = s;
            }
            float sq = h[0] * h[0] + h[1] * h[1] + h[2] * h[2];
            ((float4*)hws)[row] = make_float4(h[0], h[1], h[2], sq);
        }
    }
}

// grid: B * 32 rowSpans = 512 blocks of 256.
// thread = 8 columns (stride 256); 64-row span prescaled into LDS as
// (-2x,-2y,-2z,sq): t = sq_r - 2*dot = 3 chained fma.
// Manual prefetch rotation: load next row before computing current one.
__global__ __launch_bounds__(256) void max_kernel(
    const float4* __restrict__ h4, int* __restrict__ acc)
{
    int bid = blockIdx.x;
    int b  = bid >> 5;
    int rb = bid & 31;
    int r0 = rb * 64;
    const float4* hb = h4 + (size_t)b * S_;
    __shared__ float4 sh[64];
    if (threadIdx.x < 64) {
        float4 rv = hb[r0 + threadIdx.x];
        sh[threadIdx.x] = make_float4(-2.f * rv.x, -2.f * rv.y, -2.f * rv.z, rv.w);
    }
    float4 hj[8];
#pragma unroll
    for (int c = 0; c < 8; ++c) hj[c] = hb[c * 256 + threadIdx.x];
    __syncthreads();
    float mc[8];
#pragma unroll
    for (int c = 0; c < 8; ++c) mc[c] = -1e30f;
    float4 rv = sh[63];
#pragma unroll 4
    for (int k = 62; k >= 0; --k) {
        float4 nx = sh[k];                       // prefetch next row
#pragma unroll
        for (int c = 0; c < 8; ++c) {
            float t = fmaf(hj[c].x, rv.x,
                      fmaf(hj[c].y, rv.y,
                      fmaf(hj[c].z, rv.z, rv.w)));   // sq_r - 2 dot
            mc[c] = fmaxf(mc[c], t);
        }
        rv = nx;
    }
#pragma unroll
    for (int c = 0; c < 8; ++c) {                // final row (rv = sh[0])
        float t = fmaf(hj[c].x, rv.x,
                  fmaf(hj[c].y, rv.y,
                  fmaf(hj[c].z, rv.z, rv.w)));
        mc[c] = fmaxf(mc[c], t);
    }
    float m = -1e30f;
#pragma unroll
    for (int c = 0; c < 8; ++c) m = fmaxf(m, mc[c] + hj[c].w);
    m = fmaxf(m, 0.f);                           // d2 >= 0
#pragma unroll
    for (int off = 32; off >= 1; off >>= 1)
        m = fmaxf(m, __shfl_xor(m, off, 64));
    __shared__ float wmax[4];
    int lane = threadIdx.x & 63, wave = threadIdx.x >> 6;
    if (lane == 0) wmax[wave] = m;
    __syncthreads();
    if (threadIdx.x == 0) {
        float mm = fmaxf(fmaxf(wmax[0], wmax[1]), fmaxf(wmax[2], wmax[3]));
        atomicMax(&acc[b * 4 + 0], __float_as_int(mm));  // d2>=0: int order == float order
    }
}

__global__ __launch_bounds__(256) void stats_kernel(
    const float4* __restrict__ h4, const float* __restrict__ theta,
    int* __restrict__ acc)
{
    int bid = blockIdx.x;
    int b  = bid >> 5;
    int rb = bid & 31;
    int r0 = rb * 64;
    const float4* hb = h4 + (size_t)b * S_;
    __shared__ float4 sh[66];                    // sh[1+k] = row r0+k, prescaled
    if (threadIdx.x < 66) {
        int r = r0 - 1 + threadIdx.x;
        r = r < 0 ? 0 : (r >= S_ ? S_ - 1 : r);
        float4 rv = hb[r];
        sh[threadIdx.x] = make_float4(-2.f * rv.x, -2.f * rv.y, -2.f * rv.z, rv.w);
    }
    float4 hj[8];
#pragma unroll
    for (int c = 0; c < 8; ++c) hj[c] = hb[c * 256 + threadIdx.x];
    __syncthreads();
    float maxd2 = __int_as_float(acc[b * 4 + 0]);
    float sig   = 1.f / (1.f + expf(-theta[0]));
    float thr2  = sig * sig * maxd2;
    float thrc[8];
#pragma unroll
    for (int c = 0; c < 8; ++c) thrc[c] = thr2 - hj[c].w;  // d2<thr2 <=> t<thrc

    // masks built descending: after loop, bit p of (mhi:mlo) = row r0+p
    unsigned mlo[8], mhi[8];
#pragma unroll
    for (int c = 0; c < 8; ++c) { mlo[c] = 0u; mhi[c] = 0u; }

    float4 rv = sh[64];                          // row r0+63
#pragma unroll 4
    for (int k = 63; k >= 32; --k) {
        float4 nx = sh[k];                       // prefetch row r0+k-1
#pragma unroll
        for (int c = 0; c < 8; ++c) {
            float t = fmaf(hj[c].x, rv.x,
                      fmaf(hj[c].y, rv.y,
                      fmaf(hj[c].z, rv.z, rv.w)));
            mhi[c] = mhi[c] * 2u + ((t < thrc[c]) ? 1u : 0u);
        }
        rv = nx;
    }
    // rv = sh[32] = row r0+31
#pragma unroll 4
    for (int k = 31; k >= 0; --k) {
        float4 nx = sh[k];                       // at k=0 prefetches sh[0] = prev row
#pragma unroll
        for (int c = 0; c < 8; ++c) {
            float t = fmaf(hj[c].x, rv.x,
                      fmaf(hj[c].y, rv.y,
                      fmaf(hj[c].z, rv.z, rv.w)));
            mlo[c] = mlo[c] * 2u + ((t < thrc[c]) ? 1u : 0u);
        }
        rv = nx;
    }
    float4 pr = rv;                              // sh[0] = row r0-1 (prescaled)
    float4 nxr = sh[65];                         // row r0+64

    int total = 0, diag = 0, vert = 0;
#pragma unroll
    for (int c = 0; c < 8; ++c) {
        int j = c * 256 + threadIdx.x;
        unsigned long long m = ((unsigned long long)mhi[c] << 32) | mlo[c];
        total += __popcll(m);
        float tp = fmaf(hj[c].x, pr.x, fmaf(hj[c].y, pr.y, fmaf(hj[c].z, pr.z, pr.w)));
        float tn = fmaf(hj[c].x, nxr.x, fmaf(hj[c].y, nxr.y, fmaf(hj[c].z, nxr.z, nxr.w)));
        unsigned long long prevbit = (r0 > 0) ? ((tp < thrc[c]) ? 1ull : 0ull) : 0ull;
        unsigned long long nextbit = (r0 + 64 < S_) ? ((tn < thrc[c]) ? 1ull : 0ull) : 0ull;
        // vertical run starts: R[i] & ~R[i-1] & R[i+1]
        unsigned long long notprev = ~((m << 1) | prevbit);
        vert += __popcll(m & notprev & ((m >> 1) | (nextbit << 63)));
        // diag band: rows s with j-s in [1,9] -> bits [j-9-r0, j-1-r0]
        int lo = j - 9 - r0, hi = j - 1 - r0;
        if (hi >= 0 && lo <= 63) {
            int l = lo < 0 ? 0 : lo;
            int h = hi > 63 ? 63 : hi;
            unsigned long long bandm = ((1ull << (h - l + 1)) - 1ull) << l;
            diag += __popcll(m & bandm);
        }
    }

    // pack (diag,vert) into 16+16 bits: after 64-lane sum diag<=4608, vert<=16384
    int dv = (diag << 16) | vert;
#pragma unroll
    for (int off = 32; off >= 1; off >>= 1) {
        total += __shfl_xor(total, off, 64);
        dv    += __shfl_xor(dv,    off, 64);
    }
    __shared__ int wsum[4][2];
    int lane = threadIdx.x & 63, wave = threadIdx.x >> 6;
    if (lane == 0) { wsum[wave][0] = total; wsum[wave][1] = dv; }
    __syncthreads();
    if (threadIdx.x == 0) {
        int t = 0, d = 0, v = 0;
#pragma unroll
        for (int w = 0; w < 4; ++w) {
            t += wsum[w][0];
            d += wsum[w][1] >> 16;
            v += wsum[w][1] & 0xFFFF;
        }
        atomicAdd(&acc[b * 4 + 1], t);
        atomicAdd(&acc[b * 4 + 2], d);
        atomicAdd(&acc[b * 4 + 3], v);
    }
}

__global__ void finalize_kernel(const int* __restrict__ acc,
    const float* __restrict__ w3, const float* __restrict__ b3,
    float* __restrict__ out)
{
    int idx = blockIdx.x * 256 + threadIdx.x;    // 0..1023
    if (idx >= B_ * OUT_DIM) return;
    int b = idx >> 6, o = idx & 63;
    float total = (float)acc[b * 4 + 1];
    float diag  = (float)acc[b * 4 + 2];
    float vert  = (float)acc[b * 4 + 3];
    float rr  = total / (float)(S_ * S_);
    float det = diag / (total + 1e-6f);
    float lam = vert / (total + 1e-6f);
    float entr = -total * logf(1.0f + 1e-6f);    // fp32 semantics (verified absmax 0.0)
    float r = b3[o] + rr  * w3[0 * OUT_DIM + o]
                    + det * w3[1 * OUT_DIM + o]
                    + lam * w3[2 * OUT_DIM + o]
                    + entr * w3[3 * OUT_DIM + o];
    out[idx] = fmaxf(r, 0.f);
}

extern "C" void kernel_launch(void* const* d_in, const int* in_sizes, int n_in,
                              void* d_out, int out_size, void* d_ws, size_t ws_size,
                              hipStream_t stream) {
    const float* x     = (const float*)d_in[0];
    const float* theta = (const float*)d_in[1];
    const float* w1    = (const float*)d_in[2];
    const float* b1    = (const float*)d_in[3];
    const float* w2    = (const float*)d_in[4];
    const float* b2    = (const float*)d_in[5];
    const float* w3    = (const float*)d_in[6];
    const float* b3    = (const float*)d_in[7];
    float* out = (float*)d_out;
    float* hws = (float*)d_ws;
    int* acc = (int*)((char*)d_ws + (size_t)B_ * S_ * 4 * sizeof(float));

    hipLaunchKernelGGL(embed_kernel, dim3(B_ * S_ / 16), dim3(256), 0, stream,
                       x, w1, b1, w2, b2, hws, acc);
    hipLaunchKernelGGL(max_kernel, dim3(B_ * 32), dim3(256), 0, stream,
                       (const float4*)hws, acc);
    hipLaunchKernelGGL(stats_kernel, dim3(B_ * 32), dim3(256), 0, stream,
                       (const float4*)hws, theta, acc);
    hipLaunchKernelGGL(finalize_kernel, dim3(4), dim3(256), 0, stream, acc, w3, b3, out);
}

// Round 11
// 110.759 us; speedup vs baseline: 1.2903x; 1.0400x over previous
//
#include <hip/hip_runtime.h>
#include <math.h>

#define B_ 16
#define S_ 2048
#define IN_DIM 128
#define E2 6
#define E_ 3
#define OUT_DIM 64

// ws layout (atomic-free since R11):
//   [0, 524288)          : h as float4 (x,y,z, sq=|h|^2)
//   [524288, 526336)     : pmax[512]  float  - per-block max partial
//   [526336, 534528)     : pstat[512] int4   - per-block {tot,diag,vert,0}
//
// R5/R6: no staged row arrays (spill). R9/R10: latency-exposure theory
// falsified (prefetch bought ~0). R11 theory: same-cache-line device atomics
// (3-4 per block into one 256B region) serialize in one L2 bank -> the
// 23-55 ns/block S2-kernel overhead embed (no atomics) doesn't pay.
// Fix: per-block plain stores + register re-reduce / tiny finalize.

// one wave per 4 rows: grid 2048 blocks of 256.
__global__ __launch_bounds__(256) void embed_kernel(
    const float* __restrict__ x, const float* __restrict__ w1,
    const float* __restrict__ b1, const float* __restrict__ w2,
    const float* __restrict__ b2, float* __restrict__ hws)
{
    int wave = threadIdx.x >> 6;
    int lane = threadIdx.x & 63;
#pragma unroll
    for (int rr = 0; rr < 4; ++rr) {
        int row = blockIdx.x * 16 + wave * 4 + rr;   // [0, B*S)
        const float2* x2 = (const float2*)(x + (size_t)row * IN_DIM);
        float2 xv = x2[lane];
        const float* w1a = w1 + (2 * lane) * E2;     // 12 contiguous floats
        float a[E2];
#pragma unroll
        for (int q = 0; q < E2; ++q)
            a[q] = xv.x * w1a[q] + xv.y * w1a[E2 + q];
#pragma unroll
        for (int q = 0; q < E2; ++q) {
#pragma unroll
            for (int off = 32; off >= 1; off >>= 1)
                a[q] += __shfl_xor(a[q], off, 64);
        }
        if (lane == 0) {
            float r[E2];
#pragma unroll
            for (int q = 0; q < E2; ++q) r[q] = fmaxf(a[q] + b1[q], 0.f);
            float h[E_];
#pragma unroll
            for (int e = 0; e < E_; ++e) {
                float s = b2[e];
#pragma unroll
                for (int q = 0; q < E2; ++q) s += r[q] * w2[q * E_ + e];
                h[e] = s;
            }
            float sq = h[0] * h[0] + h[1] * h[1] + h[2] * h[2];
            ((float4*)hws)[row] = make_float4(h[0], h[1], h[2], sq);
        }
    }
}

// grid: B * 32 rowSpans = 512 blocks of 256.
// thread = 8 columns (stride 256); 64-row span prescaled into LDS as
// (-2x,-2y,-2z,sq): t = sq_r - 2*dot = 3 chained fma.
__global__ __launch_bounds__(256) void max_kernel(
    const float4* __restrict__ h4, float* __restrict__ pmax)
{
    int bid = blockIdx.x;
    int b  = bid >> 5;
    int rb = bid & 31;
    int r0 = rb * 64;
    const float4* hb = h4 + (size_t)b * S_;
    __shared__ float4 sh[64];
    if (threadIdx.x < 64) {
        float4 rv = hb[r0 + threadIdx.x];
        sh[threadIdx.x] = make_float4(-2.f * rv.x, -2.f * rv.y, -2.f * rv.z, rv.w);
    }
    float4 hj[8];
#pragma unroll
    for (int c = 0; c < 8; ++c) hj[c] = hb[c * 256 + threadIdx.x];
    __syncthreads();
    float mc[8];
#pragma unroll
    for (int c = 0; c < 8; ++c) mc[c] = -1e30f;
    float4 rv = sh[63];
#pragma unroll 4
    for (int k = 62; k >= 0; --k) {
        float4 nx = sh[k];                       // prefetch next row
#pragma unroll
        for (int c = 0; c < 8; ++c) {
            float t = fmaf(hj[c].x, rv.x,
                      fmaf(hj[c].y, rv.y,
                      fmaf(hj[c].z, rv.z, rv.w)));   // sq_r - 2 dot
            mc[c] = fmaxf(mc[c], t);
        }
        rv = nx;
    }
#pragma unroll
    for (int c = 0; c < 8; ++c) {                // final row (rv = sh[0])
        float t = fmaf(hj[c].x, rv.x,
                  fmaf(hj[c].y, rv.y,
                  fmaf(hj[c].z, rv.z, rv.w)));
        mc[c] = fmaxf(mc[c], t);
    }
    float m = -1e30f;
#pragma unroll
    for (int c = 0; c < 8; ++c) m = fmaxf(m, mc[c] + hj[c].w);
    m = fmaxf(m, 0.f);                           // d2 >= 0
#pragma unroll
    for (int off = 32; off >= 1; off >>= 1)
        m = fmaxf(m, __shfl_xor(m, off, 64));
    __shared__ float wmax[4];
    int lane = threadIdx.x & 63, wave = threadIdx.x >> 6;
    if (lane == 0) wmax[wave] = m;
    __syncthreads();
    if (threadIdx.x == 0) {
        float mm = fmaxf(fmaxf(wmax[0], wmax[1]), fmaxf(wmax[2], wmax[3]));
        pmax[bid] = mm;                          // plain store - no atomic
    }
}

__global__ __launch_bounds__(256) void stats_kernel(
    const float4* __restrict__ h4, const float* __restrict__ theta,
    const float* __restrict__ pmax, int4* __restrict__ pstat)
{
    int bid = blockIdx.x;
    int b  = bid >> 5;
    int rb = bid & 31;
    int r0 = rb * 64;
    const float4* hb = h4 + (size_t)b * S_;
    __shared__ float4 sh[66];                    // sh[1+k] = row r0+k, prescaled
    if (threadIdx.x < 66) {
        int r = r0 - 1 + threadIdx.x;
        r = r < 0 ? 0 : (r >= S_ ? S_ - 1 : r);
        float4 rv = hb[r];
        sh[threadIdx.x] = make_float4(-2.f * rv.x, -2.f * rv.y, -2.f * rv.z, rv.w);
    }
    float4 hj[8];
#pragma unroll
    for (int c = 0; c < 8; ++c) hj[c] = hb[c * 256 + threadIdx.x];
    __syncthreads();

    // re-reduce this batch's 32 pmax partials in-register (no extra dispatch)
    int lane = threadIdx.x & 63;
    float pm = pmax[b * 32 + (lane & 31)];
#pragma unroll
    for (int off = 16; off >= 1; off >>= 1)
        pm = fmaxf(pm, __shfl_xor(pm, off, 64));
    float maxd2 = pm;

    float sig   = 1.f / (1.f + expf(-theta[0]));
    float thr2  = sig * sig * maxd2;
    float thrc[8];
#pragma unroll
    for (int c = 0; c < 8; ++c) thrc[c] = thr2 - hj[c].w;  // d2<thr2 <=> t<thrc

    // masks built descending: after loop, bit p of (mhi:mlo) = row r0+p
    unsigned mlo[8], mhi[8];
#pragma unroll
    for (int c = 0; c < 8; ++c) { mlo[c] = 0u; mhi[c] = 0u; }

    float4 rv = sh[64];                          // row r0+63
#pragma unroll 4
    for (int k = 63; k >= 32; --k) {
        float4 nx = sh[k];                       // prefetch row r0+k-1
#pragma unroll
        for (int c = 0; c < 8; ++c) {
            float t = fmaf(hj[c].x, rv.x,
                      fmaf(hj[c].y, rv.y,
                      fmaf(hj[c].z, rv.z, rv.w)));
            mhi[c] = mhi[c] * 2u + ((t < thrc[c]) ? 1u : 0u);
        }
        rv = nx;
    }
    // rv = sh[32] = row r0+31
#pragma unroll 4
    for (int k = 31; k >= 0; --k) {
        float4 nx = sh[k];                       // at k=0 prefetches sh[0] = prev row
#pragma unroll
        for (int c = 0; c < 8; ++c) {
            float t = fmaf(hj[c].x, rv.x,
                      fmaf(hj[c].y, rv.y,
                      fmaf(hj[c].z, rv.z, rv.w)));
            mlo[c] = mlo[c] * 2u + ((t < thrc[c]) ? 1u : 0u);
        }
        rv = nx;
    }
    float4 pr = rv;                              // sh[0] = row r0-1 (prescaled)
    float4 nxr = sh[65];                         // row r0+64

    int total = 0, diag = 0, vert = 0;
#pragma unroll
    for (int c = 0; c < 8; ++c) {
        int j = c * 256 + threadIdx.x;
        unsigned long long m = ((unsigned long long)mhi[c] << 32) | mlo[c];
        total += __popcll(m);
        float tp = fmaf(hj[c].x, pr.x, fmaf(hj[c].y, pr.y, fmaf(hj[c].z, pr.z, pr.w)));
        float tn = fmaf(hj[c].x, nxr.x, fmaf(hj[c].y, nxr.y, fmaf(hj[c].z, nxr.z, nxr.w)));
        unsigned long long prevbit = (r0 > 0) ? ((tp < thrc[c]) ? 1ull : 0ull) : 0ull;
        unsigned long long nextbit = (r0 + 64 < S_) ? ((tn < thrc[c]) ? 1ull : 0ull) : 0ull;
        // vertical run starts: R[i] & ~R[i-1] & R[i+1]
        unsigned long long notprev = ~((m << 1) | prevbit);
        vert += __popcll(m & notprev & ((m >> 1) | (nextbit << 63)));
        // diag band: rows s with j-s in [1,9] -> bits [j-9-r0, j-1-r0]
        int lo = j - 9 - r0, hi = j - 1 - r0;
        if (hi >= 0 && lo <= 63) {
            int l = lo < 0 ? 0 : lo;
            int h = hi > 63 ? 63 : hi;
            unsigned long long bandm = ((1ull << (h - l + 1)) - 1ull) << l;
            diag += __popcll(m & bandm);
        }
    }

    // pack (diag,vert) into 16+16 bits: after 64-lane sum diag<=4608, vert<=16384
    int dv = (diag << 16) | vert;
#pragma unroll
    for (int off = 32; off >= 1; off >>= 1) {
        total += __shfl_xor(total, off, 64);
        dv    += __shfl_xor(dv,    off, 64);
    }
    __shared__ int wsum[4][2];
    int wave = threadIdx.x >> 6;
    if (lane == 0) { wsum[wave][0] = total; wsum[wave][1] = dv; }
    __syncthreads();
    if (threadIdx.x == 0) {
        int t = 0, d = 0, v = 0;
#pragma unroll
        for (int w = 0; w < 4; ++w) {
            t += wsum[w][0];
            d += wsum[w][1] >> 16;
            v += wsum[w][1] & 0xFFFF;
        }
        pstat[bid] = make_int4(t, d, v, 0);      // plain store - no atomic
    }
}

// one block of 256 threads: reduce 512 int4 partials, emit 1024 outputs
__global__ __launch_bounds__(256) void finalize_kernel(
    const int4* __restrict__ pstat,
    const float* __restrict__ w3, const float* __restrict__ b3,
    float* __restrict__ out)
{
    __shared__ float stot[16], sdia[16], sver[16];
    int tid = threadIdx.x;
    if (tid < 16) {
        int t = 0, d = 0, v = 0;
        for (int i = 0; i < 32; ++i) {
            int4 p = pstat[tid * 32 + i];
            t += p.x; d += p.y; v += p.z;
        }
        stot[tid] = (float)t; sdia[tid] = (float)d; sver[tid] = (float)v;
    }
    __syncthreads();
#pragma unroll
    for (int q = 0; q < 4; ++q) {
        int idx = q * 256 + tid;                 // 0..1023
        int b = idx >> 6, o = idx & 63;
        float total = stot[b], diag = sdia[b], vert = sver[b];
        float rr  = total / (float)(S_ * S_);
        float det = diag / (total + 1e-6f);
        float lam = vert / (total + 1e-6f);
        float entr = -total * logf(1.0f + 1e-6f);  // fp32 semantics (absmax 0 verified)
        float r = b3[o] + rr  * w3[0 * OUT_DIM + o]
                        + det * w3[1 * OUT_DIM + o]
                        + lam * w3[2 * OUT_DIM + o]
                        + entr * w3[3 * OUT_DIM + o];
        out[idx] = fmaxf(r, 0.f);
    }
}

extern "C" void kernel_launch(void* const* d_in, const int* in_sizes, int n_in,
                              void* d_out, int out_size, void* d_ws, size_t ws_size,
                              hipStream_t stream) {
    const float* x     = (const float*)d_in[0];
    const float* theta = (const float*)d_in[1];
    const float* w1    = (const float*)d_in[2];
    const float* b1    = (const float*)d_in[3];
    const float* w2    = (const float*)d_in[4];
    const float* b2    = (const float*)d_in[5];
    const float* w3    = (const float*)d_in[6];
    const float* b3    = (const float*)d_in[7];
    float* out = (float*)d_out;
    float* hws = (float*)d_ws;
    float* pmax = (float*)((char*)d_ws + 524288);
    int4*  pstat = (int4*)((char*)d_ws + 526336);

    hipLaunchKernelGGL(embed_kernel, dim3(B_ * S_ / 16), dim3(256), 0, stream,
                       x, w1, b1, w2, b2, hws);
    hipLaunchKernelGGL(max_kernel, dim3(B_ * 32), dim3(256), 0, stream,
                       (const float4*)hws, pmax);
    hipLaunchKernelGGL(stats_kernel, dim3(B_ * 32), dim3(256), 0, stream,
                       (const float4*)hws, theta, pmax, pstat);
    hipLaunchKernelGGL(finalize_kernel, dim3(1), dim3(256), 0, stream,
                       pstat, w3, b3, out);
}